// Round 3
// baseline (92.217 us; speedup 1.0000x reference)
//
#include <hip/hip_runtime.h>
#include <math.h>

#define NQ   12
#define DIM  4096          // 2^12 amplitudes
#define BLK  256           // threads per block; 16 complex amplitudes per thread
#define NPAR 144           // 3 layers * 4 groups * 12 qubits

// XOR swizzle on the float2 index: for any contiguous-6-bit lane-varying window
// (all rotations k), low address bits get independent lane bits -> uniform
// lanes/bank-pair, conflict-minimal b64 access at every rotation.
__device__ __forceinline__ int swz(int i) { return i ^ ((i >> 6) & 63); }

__device__ __forceinline__ int rotl12(int x, int k) {
    return ((x << k) | (x >> (12 - k))) & 4095;    // k in [0,11]
}

// RY on register-local bit with mask M: 8 pairs, fully unrolled (constant indices).
template<int M>
__device__ __forceinline__ void ry_reg(float (&xr)[16], float (&xi)[16], float c, float s) {
    #pragma unroll
    for (int p = 0; p < 8; ++p) {
        const int r0 = ((p & ~(M - 1)) << 1) | (p & (M - 1));
        const int r1 = r0 | M;
        float a = xr[r0], b = xr[r1];
        xr[r0] = c * a - s * b;
        xr[r1] = s * a + c * b;
        float u = xi[r0], v = xi[r1];
        xi[r0] = c * u - s * v;
        xi[r1] = s * u + c * v;
    }
}

// CRX control mask MC, target mask MT: 4 pairs in control=1 subspace.
// off-diagonal coefficient -i*s: r0' = c*r0 + s*q1 ; q0' = c*q0 - s*r1 (validated R1/R2).
template<int MC, int MT>
__device__ __forceinline__ void crx_reg(float (&xr)[16], float (&xi)[16], float c, float s) {
    constexpr int mlo = (MC < MT) ? MC : MT;
    constexpr int mhi = (MC < MT) ? MT : MC;
    #pragma unroll
    for (int p = 0; p < 4; ++p) {
        int q = ((p & ~(mlo - 1)) << 1) | (p & (mlo - 1));
        q     = ((q & ~(mhi - 1)) << 1) | (q & (mhi - 1));
        const int r0 = q | MC;
        const int r1 = r0 | MT;
        float ar = xr[r0], br = xr[r1], ai = xi[r0], bi = xi[r1];
        xr[r0] = c * ar + s * bi;
        xi[r0] = c * ai - s * br;
        xr[r1] = c * br + s * ai;
        xi[r1] = c * bi - s * ar;
    }
}

// Double-buffered restage: write regs (rotation kold) into dst, ONE barrier,
// read back at rotation knew. dst alternates per call; the WAR hazard against
// the 2-epochs-ago reads of dst is covered transitively by the previous
// restage's barrier.
__device__ __forceinline__ void restage(float2* dst, float (&xr)[16], float (&xi)[16],
                                        int tb, int kold, int knew) {
    #pragma unroll
    for (int r = 0; r < 16; ++r)
        dst[swz(rotl12(tb | r, kold))] = make_float2(xr[r], xi[r]);
    __syncthreads();
    #pragma unroll
    for (int r = 0; r < 16; ++r) {
        float2 v = dst[swz(rotl12(tb | r, knew))];
        xr[r] = v.x; xi[r] = v.y;
    }
}

// RY window: local j=0..3 -> masks 1,2,4,8, angle indices base+a0..a3
#define RY4(a0,a1,a2,a3) \
    ry_reg<1>(xr, xi, cs_s[base+(a0)], sn_s[base+(a0)]); \
    ry_reg<2>(xr, xi, cs_s[base+(a1)], sn_s[base+(a1)]); \
    ry_reg<4>(xr, xi, cs_s[base+(a2)], sn_s[base+(a2)]); \
    ry_reg<8>(xr, xi, cs_s[base+(a3)], sn_s[base+(a3)]);

// Group-1 CRX triplet (ascending): local (jc,jt)=(1,0),(2,1),(3,2)
#define CRX3_UP(i0) \
    crx_reg<2,1>(xr, xi, cs_s[base+12+(i0)],   sn_s[base+12+(i0)]); \
    crx_reg<4,2>(xr, xi, cs_s[base+12+(i0)+1], sn_s[base+12+(i0)+1]); \
    crx_reg<8,4>(xr, xi, cs_s[base+12+(i0)+2], sn_s[base+12+(i0)+2]);

// Group-3 CRX triplet (descending): local (jc,jt)=(2,3),(1,2),(0,1)
#define CRX3_DN(i0) \
    crx_reg<4,8>(xr, xi, cs_s[base+36+(i0)],   sn_s[base+36+(i0)]); \
    crx_reg<2,4>(xr, xi, cs_s[base+36+(i0)+1], sn_s[base+36+(i0)+1]); \
    crx_reg<1,2>(xr, xi, cs_s[base+36+(i0)+2], sn_s[base+36+(i0)+2]);

#define RESTAGE(kold, knew) \
    restage(cur, xr, xi, tb, kold, knew); cur = (cur == lds0) ? lds1 : lds0;

__global__ __launch_bounds__(BLK) void ansatz_kernel(
    const float* __restrict__ sre, const float* __restrict__ sim,
    const float* __restrict__ params, float* __restrict__ out) {

    __shared__ float2 buf[2][DIM];     // double-buffered swizzled state, 64 KB
    __shared__ float  cs_s[NPAR], sn_s[NPAR];
    float2* lds0 = buf[0];
    float2* lds1 = buf[1];

    const int b   = blockIdx.x;
    const int tid = threadIdx.x;
    const int tb  = tid << 4;

    // coalesced global -> swizzled LDS (buf0)
    for (int i = tid; i < DIM; i += BLK)
        lds0[swz(i)] = make_float2(sre[b * DIM + i], sim[b * DIM + i]);
    for (int i = tid; i < NPAR; i += BLK) {
        float s, c;
        sincosf(0.5f * params[b * NPAR + i], &s, &c);
        cs_s[i] = c; sn_s[i] = s;
    }
    __syncthreads();

    // initial localization: rotation k=3 (canonical bits 3..6 register-local)
    float xr[16], xi[16];
    #pragma unroll
    for (int r = 0; r < 16; ++r) {
        float2 v = lds0[swz(rotl12(tb | r, 3))];
        xr[r] = v.x; xi[r] = v.y;
    }
    float2* cur = lds1;                 // next restage destination

    for (int l = 0; l < 3; ++l) {
        const int base = 48 * l;
        if (l) { RESTAGE(1, 3) }
        RY4(8, 7, 6, 5)                 // k=3 : RY qubits 8,7,6,5
        RESTAGE(3, 7)
        RY4(4, 3, 2, 1)                 // k=7 : RY qubits 4,3,2,1
        RESTAGE(7, 11)
        RY4(0, 11, 10, 9)               // k=11: RY qubits 0,11,10,9
        CRX3_UP(0)                      // k=11: CRX g1 i=0,1,2
        RESTAGE(11, 2)
        CRX3_UP(3)                      // k=2 : i=3,4,5
        RESTAGE(2, 5)
        CRX3_UP(6)                      // k=5 : i=6,7,8
        RESTAGE(5, 8)
        CRX3_UP(9)                      // k=8 : i=9,10,11
        RY4(27, 26, 25, 24)             // k=8 : RY g2 qubits 3,2,1,0
        RESTAGE(8, 0)
        RY4(35, 34, 33, 32)             // k=0 : RY g2 qubits 11,10,9,8
        RESTAGE(0, 4)
        RY4(31, 30, 29, 28)             // k=4 : RY g2 qubits 7,6,5,4
        RESTAGE(4, 10)
        CRX3_DN(0)                      // k=10: CRX g3 i=0,1,2
        RESTAGE(10, 7)
        CRX3_DN(3)                      // k=7 : i=3,4,5
        RESTAGE(7, 4)
        CRX3_DN(6)                      // k=4 : i=6,7,8
        RESTAGE(4, 1)
        CRX3_DN(9)                      // k=1 : i=9,10,11
    }

    // final: regs (k=1) -> canonical LDS (fresh buffer, no WAR barrier needed)
    #pragma unroll
    for (int r = 0; r < 16; ++r)
        cur[swz(rotl12(tb | r, 1))] = make_float2(xr[r], xi[r]);
    __syncthreads();
    float2* out2 = (float2*)out + (size_t)b * DIM;
    for (int i = tid; i < DIM; i += BLK)
        out2[i] = cur[swz(i)];
}

extern "C" void kernel_launch(void* const* d_in, const int* in_sizes, int n_in,
                              void* d_out, int out_size, void* d_ws, size_t ws_size,
                              hipStream_t stream) {
    const float* sre    = (const float*)d_in[0];
    const float* sim    = (const float*)d_in[1];
    const float* params = (const float*)d_in[2];
    float* out          = (float*)d_out;

    const int B = in_sizes[0] / DIM;   // 128
    ansatz_kernel<<<B, BLK, 0, stream>>>(sre, sim, params, out);
}